// Round 1
// baseline (432.207 us; speedup 1.0000x reference)
//
#include <hip/hip_runtime.h>
#include <hip/hip_bf16.h>

// Problem constants
#define B_    2
#define T_    2048
#define C_    1024
#define H_    16
#define D_    64
#define SRCL_ 128

typedef short  short8 __attribute__((ext_vector_type(8)));   // 8 bf16 (4 VGPRs)
typedef float  f32x4  __attribute__((ext_vector_type(4)));
typedef unsigned short ushort4_t __attribute__((ext_vector_type(4)));

__device__ inline unsigned short f2bf(float f) {
    union { float f; unsigned u; } v; v.f = f;
    unsigned r = v.u + 0x7FFFu + ((v.u >> 16) & 1u);   // RNE
    return (unsigned short)(r >> 16);
}

// ---------------------------------------------------------------------------
// Kernel 1: fp32 -> bf16 conversion of x and the three weight matrices.
// x: 4096*1024 floats -> xb ; Wq/Wk/Wv: 1024*1024 each -> wb (concatenated).
// ---------------------------------------------------------------------------
__global__ __launch_bounds__(256) void convert_all(
        const float* __restrict__ x,
        const float* __restrict__ wq,
        const float* __restrict__ wk,
        const float* __restrict__ wv,
        unsigned short* __restrict__ xb,
        unsigned short* __restrict__ wb)
{
    const int NX = (B_ * T_ * C_) / 4;     // 1,048,576 float4 chunks
    const int NW = (C_ * C_) / 4;          // 262,144 per weight
    int i = blockIdx.x * 256 + threadIdx.x;
    const float4* src;
    ushort4_t* dst;
    if (i < NX)               { src = (const float4*)x;  dst = (ushort4_t*)xb;                }
    else if (i < NX + NW)     { src = (const float4*)wq; dst = (ushort4_t*)wb;                i -= NX; }
    else if (i < NX + 2*NW)   { src = (const float4*)wk; dst = (ushort4_t*)(wb + C_*C_);      i -= NX + NW; }
    else                      { src = (const float4*)wv; dst = (ushort4_t*)(wb + 2*C_*C_);    i -= NX + 2*NW; }
    float4 v = src[i];
    ushort4_t o;
    o.x = f2bf(v.x); o.y = f2bf(v.y); o.z = f2bf(v.z); o.w = f2bf(v.w);
    dst[i] = o;
}

// ---------------------------------------------------------------------------
// Kernel 2: fused QKV projection GEMM.
// C[i,j] = sum_k xb[i,k] * wb[j,k] + bias[j]    (M=4096, N=3072, K=1024)
// Output written as bf16 into q/k/v buffers with layout [B, H, T, D].
// 128x128 tile, BK=32, 256 threads = 4 waves (2x2), 4x4 MFMA tiles per wave.
// ---------------------------------------------------------------------------
__global__ __launch_bounds__(256) void gemm_qkv(
        const unsigned short* __restrict__ xb,   // [4096,1024]
        const unsigned short* __restrict__ wb,   // [3072,1024]
        const float* __restrict__ bq,
        const float* __restrict__ bk,
        const float* __restrict__ bv,
        unsigned short* __restrict__ qo,         // [B,H,T,D]
        unsigned short* __restrict__ ko,         // [B,H,T,D]
        unsigned short* __restrict__ vo)         // [B,H,T,D]
{
    __shared__ __align__(16) unsigned short As[128 * 48];  // stride 48 elems = 96B (16B aligned rows)
    __shared__ __align__(16) unsigned short Bs[128 * 48];

    const int tid  = threadIdx.x;
    const int wave = tid >> 6;
    const int lane = tid & 63;
    const int lane15 = lane & 15;
    const int quad   = lane >> 4;
    const int wm = wave >> 1;       // 0..1
    const int wn = wave & 1;        // 0..1
    const int m0 = (blockIdx.x & 31) * 128;   // 32 m-tiles
    const int n0 = (blockIdx.x >> 5) * 128;   // 24 n-tiles

    f32x4 acc[4][4];
#pragma unroll
    for (int mi = 0; mi < 4; ++mi)
#pragma unroll
        for (int ni = 0; ni < 4; ++ni)
            acc[mi][ni] = (f32x4){0.f, 0.f, 0.f, 0.f};

    // staging assignment: 512 chunks of 8 bf16 (16B); 2 chunks per thread
    const int c0  = tid * 2;
    const int rA0 = c0 >> 2;            // 4 chunks per 32-col row
    const int cA0 = (c0 & 3) * 8;
    const int rA1 = (c0 + 1) >> 2;
    const int cA1 = ((c0 + 1) & 3) * 8;

    for (int k0 = 0; k0 < 1024; k0 += 32) {
        *(short8*)&As[rA0 * 48 + cA0] = *(const short8*)&xb[(m0 + rA0) * 1024 + k0 + cA0];
        *(short8*)&As[rA1 * 48 + cA1] = *(const short8*)&xb[(m0 + rA1) * 1024 + k0 + cA1];
        *(short8*)&Bs[rA0 * 48 + cA0] = *(const short8*)&wb[(n0 + rA0) * 1024 + k0 + cA0];
        *(short8*)&Bs[rA1 * 48 + cA1] = *(const short8*)&wb[(n0 + rA1) * 1024 + k0 + cA1];
        __syncthreads();

        short8 a[4], bf[4];
#pragma unroll
        for (int mi = 0; mi < 4; ++mi)
            a[mi] = *(const short8*)&As[(wm * 64 + mi * 16 + lane15) * 48 + quad * 8];
#pragma unroll
        for (int ni = 0; ni < 4; ++ni)
            bf[ni] = *(const short8*)&Bs[(wn * 64 + ni * 16 + lane15) * 48 + quad * 8];
#pragma unroll
        for (int mi = 0; mi < 4; ++mi)
#pragma unroll
            for (int ni = 0; ni < 4; ++ni)
                acc[mi][ni] = __builtin_amdgcn_mfma_f32_16x16x32_bf16(a[mi], bf[ni], acc[mi][ni], 0, 0, 0);
        __syncthreads();
    }

    // epilogue: bias add, bf16 cast, scatter into [B,H,T,D] per-head layout
#pragma unroll
    for (int ni = 0; ni < 4; ++ni) {
        const int col   = n0 + wn * 64 + ni * 16 + lane15;   // 0..3071
        const int which = col >> 10;                          // 0=q 1=k 2=v
        const int jj    = col & 1023;
        const float bias = (which == 0 ? bq : (which == 1 ? bk : bv))[jj];
        unsigned short* dst = (which == 0 ? qo : (which == 1 ? ko : vo));
        const int h = jj >> 6;
        const int d = jj & 63;
#pragma unroll
        for (int mi = 0; mi < 4; ++mi) {
#pragma unroll
            for (int r = 0; r < 4; ++r) {
                const int rowg = m0 + wm * 64 + mi * 16 + quad * 4 + r;  // 0..4095
                const int bidx = rowg >> 11;
                const int t    = rowg & 2047;
                const float val = acc[mi][ni][r] + bias;
                dst[((((size_t)bidx * H_ + h) * T_ + t) << 6) + d] = f2bf(val);
            }
        }
    }
}

// ---------------------------------------------------------------------------
// Kernel 3: transpose V [B,H,T,D] -> VT [B,H,D,T] (64x64 tiles through LDS)
// ---------------------------------------------------------------------------
__global__ __launch_bounds__(256) void transpose_v(
        const unsigned short* __restrict__ v_,
        unsigned short* __restrict__ vt)
{
    __shared__ __align__(16) unsigned short tile[64 * 80];   // stride 80 elems = 160B
    const int bh = blockIdx.x >> 5;
    const int t0 = (blockIdx.x & 31) * 64;
    const unsigned short* src = v_ + (size_t)bh * T_ * D_;
    unsigned short* dst       = vt + (size_t)bh * D_ * T_;
    const int tid = threadIdx.x;

#pragma unroll
    for (int cc = 0; cc < 2; ++cc) {
        const int c  = tid * 2 + cc;
        const int tr = c >> 3;          // 0..63  (t row)
        const int d0 = (c & 7) * 8;     // d col start
        union { short8 v; unsigned short u[8]; } val;
        val.v = *(const short8*)&src[(t0 + tr) * 64 + d0];
#pragma unroll
        for (int j = 0; j < 8; ++j)
            tile[(d0 + j) * 80 + tr] = val.u[j];
    }
    __syncthreads();
#pragma unroll
    for (int cc = 0; cc < 2; ++cc) {
        const int c  = tid * 2 + cc;
        const int dr = c >> 3;          // d row
        const int tc = (c & 7) * 8;     // t col start
        *(short8*)&dst[(size_t)dr * T_ + t0 + tc] = *(const short8*)&tile[dr * 80 + tc];
    }
}

// ---------------------------------------------------------------------------
// Kernel 4: flash-style banded-causal attention.
// One block per (b,h, 64-row q-tile); 4 waves x 16 q-rows each.
// K-tiles of 64 keys; loop truncated at qt*64+192 (mask j <= i + 128).
// ---------------------------------------------------------------------------
__global__ __launch_bounds__(256) void attn(
        const unsigned short* __restrict__ qg,   // [B,H,T,D]
        const unsigned short* __restrict__ kg,   // [B,H,T,D]
        const unsigned short* __restrict__ vtg,  // [B,H,D,T]
        float* __restrict__ out)                 // [B,T,C] fp32
{
    __shared__ __align__(16) unsigned short Ps[4][16 * 80];  // per-wave P: 16 rows x 64 keys, stride 80

    const int tid  = threadIdx.x;
    const int wave = tid >> 6;
    const int lane = tid & 63;
    const int lane15 = lane & 15;
    const int quad   = lane >> 4;
    const int bh = blockIdx.x >> 5;
    const int qt = blockIdx.x & 31;
    const int b  = bh >> 4;
    const int h  = bh & 15;
    const int i0 = qt * 64 + wave * 16;          // this wave's first q row

    const unsigned short* Q  = qg  + (size_t)bh * T_ * D_;
    const unsigned short* K  = kg  + (size_t)bh * T_ * D_;
    const unsigned short* VT = vtg + (size_t)bh * D_ * T_;

    // Q fragments (reused across all K tiles): A[m=lane15][k=quad*8+j]
    short8 qf0 = *(const short8*)&Q[(i0 + lane15) * 64 + quad * 8];
    short8 qf1 = *(const short8*)&Q[(i0 + lane15) * 64 + 32 + quad * 8];

    f32x4 o_acc[4];
#pragma unroll
    for (int di = 0; di < 4; ++di) o_acc[di] = (f32x4){0.f, 0.f, 0.f, 0.f};
    float m_r[4] = {-1e30f, -1e30f, -1e30f, -1e30f};
    float l_r[4] = {0.f, 0.f, 0.f, 0.f};

    const int jmax = min(T_, qt * 64 + 64 + SRCL_);   // exclusive

    for (int j0 = 0; j0 < jmax; j0 += 64) {
        // ---- S = Q K^T (4 column tiles of 16 keys) ----
        f32x4 s[4];
#pragma unroll
        for (int ni = 0; ni < 4; ++ni) {
            const unsigned short* Krow = &K[(j0 + ni * 16 + lane15) * 64 + quad * 8];
            short8 kf0 = *(const short8*)Krow;
            short8 kf1 = *(const short8*)(Krow + 32);
            f32x4 t = (f32x4){0.f, 0.f, 0.f, 0.f};
            t = __builtin_amdgcn_mfma_f32_16x16x32_bf16(qf0, kf0, t, 0, 0, 0);
            t = __builtin_amdgcn_mfma_f32_16x16x32_bf16(qf1, kf1, t, 0, 0, 0);
            s[ni] = t;
        }

        const bool needMask = (j0 + 63 > i0 + SRCL_);

        // ---- online softmax per row (row = quad*4 + r, cols across 16 lanes) ----
#pragma unroll
        for (int r = 0; r < 4; ++r) {
            const int qi = i0 + quad * 4 + r;
            float pv[4];
            float mx = m_r[r];
#pragma unroll
            for (int ni = 0; ni < 4; ++ni) {
                float sv = s[ni][r] * 0.125f;
                if (needMask && (j0 + ni * 16 + lane15) > qi + SRCL_) sv = -1e30f;
                pv[ni] = sv;
                mx = fmaxf(mx, sv);
            }
            mx = fmaxf(mx, __shfl_xor(mx, 1));
            mx = fmaxf(mx, __shfl_xor(mx, 2));
            mx = fmaxf(mx, __shfl_xor(mx, 4));
            mx = fmaxf(mx, __shfl_xor(mx, 8));
            const float alpha = __expf(m_r[r] - mx);
            m_r[r] = mx;
            float rs = 0.f;
#pragma unroll
            for (int ni = 0; ni < 4; ++ni) {
                float p = __expf(pv[ni] - mx);
                pv[ni] = p;
                rs += p;
            }
            rs += __shfl_xor(rs, 1);
            rs += __shfl_xor(rs, 2);
            rs += __shfl_xor(rs, 4);
            rs += __shfl_xor(rs, 8);
            l_r[r] = l_r[r] * alpha + rs;
#pragma unroll
            for (int di = 0; di < 4; ++di) {
                o_acc[di][0 + r] *= alpha;   // scale row r of each d-tile acc
            }
            // write P row to per-wave LDS (C layout -> [row][key] matrix)
#pragma unroll
            for (int ni = 0; ni < 4; ++ni)
                Ps[wave][(quad * 4 + r) * 80 + ni * 16 + lane15] = f2bf(pv[ni]);
        }
        __syncthreads();

        // ---- O += P V : P A-frags from LDS, V B-frags from VT (contiguous in key) ----
        short8 pf0 = *(const short8*)&Ps[wave][lane15 * 80 + quad * 8];
        short8 pf1 = *(const short8*)&Ps[wave][lane15 * 80 + 32 + quad * 8];
#pragma unroll
        for (int di = 0; di < 4; ++di) {
            const unsigned short* Vcol = &VT[(size_t)(di * 16 + lane15) * T_ + j0 + quad * 8];
            short8 vf0 = *(const short8*)Vcol;
            short8 vf1 = *(const short8*)(Vcol + 32);
            o_acc[di] = __builtin_amdgcn_mfma_f32_16x16x32_bf16(pf0, vf0, o_acc[di], 0, 0, 0);
            o_acc[di] = __builtin_amdgcn_mfma_f32_16x16x32_bf16(pf1, vf1, o_acc[di], 0, 0, 0);
        }
        __syncthreads();
    }

    // ---- epilogue: out[b, t, h*64+d] = O / l ----
#pragma unroll
    for (int di = 0; di < 4; ++di) {
        const int d = di * 16 + lane15;
#pragma unroll
        for (int r = 0; r < 4; ++r) {
            const int t = i0 + quad * 4 + r;
            out[((size_t)(b * T_ + t)) * C_ + h * 64 + d] = o_acc[di][r] / l_r[r];
        }
    }
}

// ---------------------------------------------------------------------------
// Launch
// ---------------------------------------------------------------------------
extern "C" void kernel_launch(void* const* d_in, const int* in_sizes, int n_in,
                              void* d_out, int out_size, void* d_ws, size_t ws_size,
                              hipStream_t stream) {
    const float* x  = (const float*)d_in[0];
    const float* Wq = (const float*)d_in[1];
    const float* bq = (const float*)d_in[2];
    const float* Wk = (const float*)d_in[3];
    const float* bk = (const float*)d_in[4];
    const float* Wv = (const float*)d_in[5];
    const float* bv = (const float*)d_in[6];
    float* out = (float*)d_out;

    // workspace layout (bf16 elements)
    unsigned short* xb  = (unsigned short*)d_ws;            // 4096*1024
    unsigned short* wb  = xb  + (size_t)B_ * T_ * C_;       // 3*1024*1024
    unsigned short* qb  = wb  + (size_t)3 * C_ * C_;        // B*H*T*D
    unsigned short* kb  = qb  + (size_t)B_ * H_ * T_ * D_;
    unsigned short* vb  = kb  + (size_t)B_ * H_ * T_ * D_;
    unsigned short* vtb = vb  + (size_t)B_ * H_ * T_ * D_;

    convert_all<<<7168, 256, 0, stream>>>(x, Wq, Wk, Wv, xb, wb);
    gemm_qkv<<<768, 256, 0, stream>>>(xb, wb, bq, bk, bv, qb, kb, vb);
    transpose_v<<<1024, 256, 0, stream>>>(vb, vtb);
    attn<<<1024, 256, 0, stream>>>(qb, kb, vtb, out);
}

// Round 2
// 367.032 us; speedup vs baseline: 1.1776x; 1.1776x over previous
//
#include <hip/hip_runtime.h>
#include <hip/hip_bf16.h>

// Problem constants
#define B_    2
#define T_    2048
#define C_    1024
#define H_    16
#define D_    64
#define SRCL_ 128

typedef short  short8 __attribute__((ext_vector_type(8)));   // 8 bf16 (4 VGPRs)
typedef float  f32x4  __attribute__((ext_vector_type(4)));
typedef unsigned short ushort4_t __attribute__((ext_vector_type(4)));

__device__ inline unsigned short f2bf(float f) {
    union { float f; unsigned u; } v; v.f = f;
    unsigned r = v.u + 0x7FFFu + ((v.u >> 16) & 1u);   // RNE
    return (unsigned short)(r >> 16);
}

// ---------------------------------------------------------------------------
// Kernel 1: fp32 -> bf16 conversion of x and the three weight matrices.
// ---------------------------------------------------------------------------
__global__ __launch_bounds__(256) void convert_all(
        const float* __restrict__ x,
        const float* __restrict__ wq,
        const float* __restrict__ wk,
        const float* __restrict__ wv,
        unsigned short* __restrict__ xb,
        unsigned short* __restrict__ wb)
{
    const int NX = (B_ * T_ * C_) / 4;     // 1,048,576 float4 chunks
    const int NW = (C_ * C_) / 4;          // 262,144 per weight
    int i = blockIdx.x * 256 + threadIdx.x;
    const float4* src;
    ushort4_t* dst;
    if (i < NX)               { src = (const float4*)x;  dst = (ushort4_t*)xb;                }
    else if (i < NX + NW)     { src = (const float4*)wq; dst = (ushort4_t*)wb;                i -= NX; }
    else if (i < NX + 2*NW)   { src = (const float4*)wk; dst = (ushort4_t*)(wb + C_*C_);      i -= NX + NW; }
    else                      { src = (const float4*)wv; dst = (ushort4_t*)(wb + 2*C_*C_);    i -= NX + 2*NW; }
    float4 v = src[i];
    ushort4_t o;
    o.x = f2bf(v.x); o.y = f2bf(v.y); o.z = f2bf(v.z); o.w = f2bf(v.w);
    dst[i] = o;
}

// ---------------------------------------------------------------------------
// Kernel 2: fused QKV projection GEMM (unchanged this round).
// C[i,j] = sum_k xb[i,k] * wb[j,k] + bias[j]    (M=4096, N=3072, K=1024)
// ---------------------------------------------------------------------------
__global__ __launch_bounds__(256) void gemm_qkv(
        const unsigned short* __restrict__ xb,   // [4096,1024]
        const unsigned short* __restrict__ wb,   // [3072,1024]
        const float* __restrict__ bq,
        const float* __restrict__ bk,
        const float* __restrict__ bv,
        unsigned short* __restrict__ qo,         // [B,H,T,D]
        unsigned short* __restrict__ ko,         // [B,H,T,D]
        unsigned short* __restrict__ vo)         // [B,H,T,D]
{
    __shared__ __align__(16) unsigned short As[128 * 48];
    __shared__ __align__(16) unsigned short Bs[128 * 48];

    const int tid  = threadIdx.x;
    const int wave = tid >> 6;
    const int lane = tid & 63;
    const int lane15 = lane & 15;
    const int quad   = lane >> 4;
    const int wm = wave >> 1;
    const int wn = wave & 1;
    const int m0 = (blockIdx.x & 31) * 128;
    const int n0 = (blockIdx.x >> 5) * 128;

    f32x4 acc[4][4];
#pragma unroll
    for (int mi = 0; mi < 4; ++mi)
#pragma unroll
        for (int ni = 0; ni < 4; ++ni)
            acc[mi][ni] = (f32x4){0.f, 0.f, 0.f, 0.f};

    const int c0  = tid * 2;
    const int rA0 = c0 >> 2;
    const int cA0 = (c0 & 3) * 8;
    const int rA1 = (c0 + 1) >> 2;
    const int cA1 = ((c0 + 1) & 3) * 8;

    for (int k0 = 0; k0 < 1024; k0 += 32) {
        *(short8*)&As[rA0 * 48 + cA0] = *(const short8*)&xb[(m0 + rA0) * 1024 + k0 + cA0];
        *(short8*)&As[rA1 * 48 + cA1] = *(const short8*)&xb[(m0 + rA1) * 1024 + k0 + cA1];
        *(short8*)&Bs[rA0 * 48 + cA0] = *(const short8*)&wb[(n0 + rA0) * 1024 + k0 + cA0];
        *(short8*)&Bs[rA1 * 48 + cA1] = *(const short8*)&wb[(n0 + rA1) * 1024 + k0 + cA1];
        __syncthreads();

        short8 a[4], bf[4];
#pragma unroll
        for (int mi = 0; mi < 4; ++mi)
            a[mi] = *(const short8*)&As[(wm * 64 + mi * 16 + lane15) * 48 + quad * 8];
#pragma unroll
        for (int ni = 0; ni < 4; ++ni)
            bf[ni] = *(const short8*)&Bs[(wn * 64 + ni * 16 + lane15) * 48 + quad * 8];
#pragma unroll
        for (int mi = 0; mi < 4; ++mi)
#pragma unroll
            for (int ni = 0; ni < 4; ++ni)
                acc[mi][ni] = __builtin_amdgcn_mfma_f32_16x16x32_bf16(a[mi], bf[ni], acc[mi][ni], 0, 0, 0);
        __syncthreads();
    }

#pragma unroll
    for (int ni = 0; ni < 4; ++ni) {
        const int col   = n0 + wn * 64 + ni * 16 + lane15;
        const int which = col >> 10;
        const int jj    = col & 1023;
        const float bias = (which == 0 ? bq : (which == 1 ? bk : bv))[jj];
        unsigned short* dst = (which == 0 ? qo : (which == 1 ? ko : vo));
        const int h = jj >> 6;
        const int d = jj & 63;
#pragma unroll
        for (int mi = 0; mi < 4; ++mi) {
#pragma unroll
            for (int r = 0; r < 4; ++r) {
                const int rowg = m0 + wm * 64 + mi * 16 + quad * 4 + r;
                const int bidx = rowg >> 11;
                const int t    = rowg & 2047;
                const float val = acc[mi][ni][r] + bias;
                dst[((((size_t)bidx * H_ + h) * T_ + t) << 6) + d] = f2bf(val);
            }
        }
    }
}

// ---------------------------------------------------------------------------
// Kernel 3: transpose V [B,H,T,D] -> VT [B,H,D,T] (unchanged).
// ---------------------------------------------------------------------------
__global__ __launch_bounds__(256) void transpose_v(
        const unsigned short* __restrict__ v_,
        unsigned short* __restrict__ vt)
{
    __shared__ __align__(16) unsigned short tile[64 * 80];
    const int bh = blockIdx.x >> 5;
    const int t0 = (blockIdx.x & 31) * 64;
    const unsigned short* src = v_ + (size_t)bh * T_ * D_;
    unsigned short* dst       = vt + (size_t)bh * D_ * T_;
    const int tid = threadIdx.x;

#pragma unroll
    for (int cc = 0; cc < 2; ++cc) {
        const int c  = tid * 2 + cc;
        const int tr = c >> 3;
        const int d0 = (c & 7) * 8;
        union { short8 v; unsigned short u[8]; } val;
        val.v = *(const short8*)&src[(t0 + tr) * 64 + d0];
#pragma unroll
        for (int j = 0; j < 8; ++j)
            tile[(d0 + j) * 80 + tr] = val.u[j];
    }
    __syncthreads();
#pragma unroll
    for (int cc = 0; cc < 2; ++cc) {
        const int c  = tid * 2 + cc;
        const int dr = c >> 3;
        const int tc = (c & 7) * 8;
        *(short8*)&dst[(size_t)dr * T_ + t0 + tc] = *(const short8*)&tile[dr * 80 + tc];
    }
}

// ---------------------------------------------------------------------------
// Kernel 4: flash attention, barrier-free per-wave design.
// Each wave owns 16 q-rows; computes S^T = K Q^T so each LANE owns a query
// column: softmax max = 2 shuffles/tile, l-sum deferred per-lane partial.
// P^T goes through per-wave LDS (ds_write_b64 x4, ds_read_b128 x2) with an
// explicit lgkmcnt wait (DS is in-order within a wave; no barrier needed).
// O^T accumulated; epilogue stores float4 to out[B,T,C].
// ---------------------------------------------------------------------------
__global__ __launch_bounds__(256) void attn(
        const unsigned short* __restrict__ qg,   // [B,H,T,D]
        const unsigned short* __restrict__ kg,   // [B,H,T,D]
        const unsigned short* __restrict__ vtg,  // [B,H,D,T]
        float* __restrict__ out)                 // [B,T,C] fp32
{
    __shared__ __align__(16) unsigned short Ps[4][16 * 80];  // per-wave P: [q=16][key=64], stride 80

    const int tid  = threadIdx.x;
    const int wave = tid >> 6;
    const int lane = tid & 63;
    const int lane15 = lane & 15;
    const int quad   = lane >> 4;

    const int g  = blockIdx.x * 4 + wave;      // 0..4095 global wave id
    const int rt = 127 - (g & 127);            // heavy (long) row-tiles dispatched first
    const int bh = g >> 7;                     // 0..31
    const int b  = bh >> 4;
    const int h  = bh & 15;
    const int i0 = rt * 16;                    // this wave's first q row

    const unsigned short* Q  = qg  + (size_t)bh * T_ * D_;
    const unsigned short* K  = kg  + (size_t)bh * T_ * D_;
    const unsigned short* VT = vtg + (size_t)bh * D_ * T_;

    // Q as B-operand fragments: B[n=lane15 (query)][k=quad*8+j (dim)]
    const short8 qf0 = *(const short8*)&Q[(i0 + lane15) * 64 + quad * 8];
    const short8 qf1 = *(const short8*)&Q[(i0 + lane15) * 64 + 32 + quad * 8];

    f32x4 o_acc[4];                            // O^T[d-tile di][q=lane15]
#pragma unroll
    for (int di = 0; di < 4; ++di) o_acc[di] = (f32x4){0.f, 0.f, 0.f, 0.f};
    float m_r = -1e30f;                        // running max for column q=lane15 (same across quads)
    float l_p = 0.f;                           // per-lane PARTIAL denom (reduced across quads at end)

    unsigned short* myPs = &Ps[wave][0];

    const int jmax = min(T_, i0 + 16 + SRCL_); // keys j < jmax can be unmasked for this wave
    for (int j0 = 0; j0 < jmax; j0 += 64) {
        // ---- S^T = K Q^T : s[ni] holds D[key = j0+ni*16+quad*4+r][query = i0+lane15]
        f32x4 s[4];
#pragma unroll
        for (int ni = 0; ni < 4; ++ni) {
            const unsigned short* Krow = &K[(j0 + ni * 16 + lane15) * 64 + quad * 8];
            short8 kf0 = *(const short8*)Krow;
            short8 kf1 = *(const short8*)(Krow + 32);
            f32x4 t = (f32x4){0.f, 0.f, 0.f, 0.f};
            t = __builtin_amdgcn_mfma_f32_16x16x32_bf16(kf0, qf0, t, 0, 0, 0);
            t = __builtin_amdgcn_mfma_f32_16x16x32_bf16(kf1, qf1, t, 0, 0, 0);
            s[ni] = t;
        }

        const bool needMask = (j0 + 63 > i0 + SRCL_);
        float tmax = m_r;
#pragma unroll
        for (int ni = 0; ni < 4; ++ni) {
#pragma unroll
            for (int r = 0; r < 4; ++r) {
                float tv = s[ni][r] * 0.125f;
                if (needMask) {
                    const int key = j0 + ni * 16 + quad * 4 + r;
                    if (key > i0 + lane15 + SRCL_) tv = -1e30f;
                }
                s[ni][r] = tv;
                tmax = fmaxf(tmax, tv);
            }
        }
        // column max: only cross-quad reduction needed (lanes l, l+16, l+32, l+48)
        tmax = fmaxf(tmax, __shfl_xor(tmax, 16));
        tmax = fmaxf(tmax, __shfl_xor(tmax, 32));
        const float alpha = __expf(m_r - tmax);
        m_r = tmax;

        float ls = 0.f;
#pragma unroll
        for (int ni = 0; ni < 4; ++ni) {
            float p0 = __expf(s[ni][0] - tmax);
            float p1 = __expf(s[ni][1] - tmax);
            float p2 = __expf(s[ni][2] - tmax);
            float p3 = __expf(s[ni][3] - tmax);
            ls += (p0 + p1) + (p2 + p3);
            uint2 w;
            w.x = (unsigned)f2bf(p0) | ((unsigned)f2bf(p1) << 16);
            w.y = (unsigned)f2bf(p2) | ((unsigned)f2bf(p3) << 16);
            // P[q=lane15][key = ni*16 + quad*4 .. +3]  (8B write)
            *(uint2*)&myPs[lane15 * 80 + ni * 16 + quad * 4] = w;
        }
        l_p = l_p * alpha + ls;
#pragma unroll
        for (int di = 0; di < 4; ++di) o_acc[di] *= alpha;

        // DS ops are in-order per wave; wave is lockstep -> waitcnt suffices.
        __asm__ volatile("s_waitcnt lgkmcnt(0)" ::: "memory");

        // P^T as B-operand: B[n=lane15 (query)][k=quad*8+j (key offset)]
        const short8 pf0 = *(const short8*)&myPs[lane15 * 80 + quad * 8];
        const short8 pf1 = *(const short8*)&myPs[lane15 * 80 + 32 + quad * 8];

        // O^T += V^T P^T : A = V^T rows (d), B = P^T
#pragma unroll
        for (int di = 0; di < 4; ++di) {
            const unsigned short* Vcol = &VT[(size_t)(di * 16 + lane15) * T_ + j0 + quad * 8];
            short8 vf0 = *(const short8*)Vcol;
            short8 vf1 = *(const short8*)(Vcol + 32);
            o_acc[di] = __builtin_amdgcn_mfma_f32_16x16x32_bf16(vf0, pf0, o_acc[di], 0, 0, 0);
            o_acc[di] = __builtin_amdgcn_mfma_f32_16x16x32_bf16(vf1, pf1, o_acc[di], 0, 0, 0);
        }
    }

    // reduce the per-lane partial denominator across the 4 quads of column q
    float l0 = l_p + __shfl_xor(l_p, 16);
    float l_tot = l0 + __shfl_xor(l0, 32);
    const float inv = 1.0f / l_tot;

    // O^T[d = di*16 + quad*4 + r][q = lane15] -> out[b][t = i0+lane15][h*64 + d]
    float* orow = out + ((size_t)(b * T_ + i0 + lane15)) * C_ + h * 64 + quad * 4;
#pragma unroll
    for (int di = 0; di < 4; ++di) {
        f32x4 v = o_acc[di] * inv;
        *(float4*)(orow + di * 16) = *(float4*)&v;
    }
}

// ---------------------------------------------------------------------------
// Launch
// ---------------------------------------------------------------------------
extern "C" void kernel_launch(void* const* d_in, const int* in_sizes, int n_in,
                              void* d_out, int out_size, void* d_ws, size_t ws_size,
                              hipStream_t stream) {
    const float* x  = (const float*)d_in[0];
    const float* Wq = (const float*)d_in[1];
    const float* bq = (const float*)d_in[2];
    const float* Wk = (const float*)d_in[3];
    const float* bk = (const float*)d_in[4];
    const float* Wv = (const float*)d_in[5];
    const float* bv = (const float*)d_in[6];
    float* out = (float*)d_out;

    unsigned short* xb  = (unsigned short*)d_ws;            // 4096*1024
    unsigned short* wb  = xb  + (size_t)B_ * T_ * C_;       // 3*1024*1024
    unsigned short* qb  = wb  + (size_t)3 * C_ * C_;        // B*H*T*D
    unsigned short* kb  = qb  + (size_t)B_ * H_ * T_ * D_;
    unsigned short* vb  = kb  + (size_t)B_ * H_ * T_ * D_;
    unsigned short* vtb = vb  + (size_t)B_ * H_ * T_ * D_;

    convert_all<<<7168, 256, 0, stream>>>(x, Wq, Wk, Wv, xb, wb);
    gemm_qkv<<<768, 256, 0, stream>>>(xb, wb, bq, bk, bv, qb, kb, vb);
    transpose_v<<<1024, 256, 0, stream>>>(vb, vtb);
    attn<<<1024, 256, 0, stream>>>(qb, kb, vtb, out);
}

// Round 3
// 319.638 us; speedup vs baseline: 1.3522x; 1.1483x over previous
//
#include <hip/hip_runtime.h>
#include <hip/hip_bf16.h>

// Problem constants
#define B_    2
#define T_    2048
#define C_    1024
#define H_    16
#define D_    64
#define SRCL_ 128

typedef short  short8 __attribute__((ext_vector_type(8)));   // 8 bf16 (4 VGPRs)
typedef float  f32x4  __attribute__((ext_vector_type(4)));
typedef unsigned short ushort4_t __attribute__((ext_vector_type(4)));

__device__ inline unsigned short f2bf(float f) {
    union { float f; unsigned u; } v; v.f = f;
    unsigned r = v.u + 0x7FFFu + ((v.u >> 16) & 1u);   // RNE
    return (unsigned short)(r >> 16);
}

// async global->LDS, 16B per lane; LDS dest = uniform base + lane*16
__device__ __forceinline__ void async_ld16(const void* g, void* l) {
    __builtin_amdgcn_global_load_lds(
        (const __attribute__((address_space(1))) unsigned int*)g,
        (__attribute__((address_space(3))) unsigned int*)l, 16, 0, 0);
}

// ---------------------------------------------------------------------------
// Kernel 1: fp32 -> bf16 conversion of x and the three weight matrices.
// ---------------------------------------------------------------------------
__global__ __launch_bounds__(256) void convert_all(
        const float* __restrict__ x,
        const float* __restrict__ wq,
        const float* __restrict__ wk,
        const float* __restrict__ wv,
        unsigned short* __restrict__ xb,
        unsigned short* __restrict__ wb)
{
    const int NX = (B_ * T_ * C_) / 4;
    const int NW = (C_ * C_) / 4;
    int i = blockIdx.x * 256 + threadIdx.x;
    const float4* src;
    ushort4_t* dst;
    if (i < NX)               { src = (const float4*)x;  dst = (ushort4_t*)xb;                }
    else if (i < NX + NW)     { src = (const float4*)wq; dst = (ushort4_t*)wb;                i -= NX; }
    else if (i < NX + 2*NW)   { src = (const float4*)wk; dst = (ushort4_t*)(wb + C_*C_);      i -= NX + NW; }
    else                      { src = (const float4*)wv; dst = (ushort4_t*)(wb + 2*C_*C_);    i -= NX + 2*NW; }
    float4 v = src[i];
    ushort4_t o;
    o.x = f2bf(v.x); o.y = f2bf(v.y); o.z = f2bf(v.z); o.w = f2bf(v.w);
    dst[i] = o;
}

// ---------------------------------------------------------------------------
// Kernel 2: fused QKV projection GEMM with global_load_lds width-16 staging.
// C[i,j] = sum_k xb[i,k] * wb[j,k] + bias[j]    (M=4096, N=3072, K=1024)
// Unpadded [128][32] LDS tiles (global_load_lds requires contiguous lane order).
// ---------------------------------------------------------------------------
__global__ __launch_bounds__(256) void gemm_qkv(
        const unsigned short* __restrict__ xb,   // [4096,1024]
        const unsigned short* __restrict__ wb,   // [3072,1024]
        const float* __restrict__ bq,
        const float* __restrict__ bk,
        const float* __restrict__ bv,
        unsigned short* __restrict__ qo,         // [B,H,T,D]
        unsigned short* __restrict__ ko,
        unsigned short* __restrict__ vo)
{
    __shared__ __align__(16) unsigned short As[128 * 32];
    __shared__ __align__(16) unsigned short Bs[128 * 32];

    const int tid  = threadIdx.x;
    const int wave = tid >> 6;
    const int lane = tid & 63;
    const int lane15 = lane & 15;
    const int quad   = lane >> 4;
    const int wm = wave >> 1;
    const int wn = wave & 1;
    const int m0 = (blockIdx.x & 31) * 128;
    const int n0 = (blockIdx.x >> 5) * 128;

    f32x4 acc[4][4];
#pragma unroll
    for (int mi = 0; mi < 4; ++mi)
#pragma unroll
        for (int ni = 0; ni < 4; ++ni)
            acc[mi][ni] = (f32x4){0.f, 0.f, 0.f, 0.f};

    // staging: 8 chunks of 1KB per matrix; wave w stages chunks {2w, 2w+1}.
    // chunk c covers rows 16c..16c+15; lane l -> row 16c + l/4, 16B piece (l%4).
    const int c0   = wave * 2;
    const int rowi0 = 16 * c0 + (lane >> 2);        // chunk c0 row
    const int rowi1 = 16 * (c0 + 1) + (lane >> 2);  // chunk c0+1 row
    const int col8 = (lane & 3) * 8;

    const unsigned short* xrow0 = &xb[(m0 + rowi0) * 1024 + col8];
    const unsigned short* xrow1 = &xb[(m0 + rowi1) * 1024 + col8];
    const unsigned short* wrow0 = &wb[(n0 + rowi0) * 1024 + col8];
    const unsigned short* wrow1 = &wb[(n0 + rowi1) * 1024 + col8];

    for (int k0 = 0; k0 < 1024; k0 += 32) {
        async_ld16(xrow0 + k0, &As[c0 * 512]);
        async_ld16(xrow1 + k0, &As[(c0 + 1) * 512]);
        async_ld16(wrow0 + k0, &Bs[c0 * 512]);
        async_ld16(wrow1 + k0, &Bs[(c0 + 1) * 512]);
        __syncthreads();

        short8 a[4], bf[4];
#pragma unroll
        for (int mi = 0; mi < 4; ++mi)
            a[mi] = *(const short8*)&As[(wm * 64 + mi * 16 + lane15) * 32 + quad * 8];
#pragma unroll
        for (int ni = 0; ni < 4; ++ni)
            bf[ni] = *(const short8*)&Bs[(wn * 64 + ni * 16 + lane15) * 32 + quad * 8];
#pragma unroll
        for (int mi = 0; mi < 4; ++mi)
#pragma unroll
            for (int ni = 0; ni < 4; ++ni)
                acc[mi][ni] = __builtin_amdgcn_mfma_f32_16x16x32_bf16(a[mi], bf[ni], acc[mi][ni], 0, 0, 0);
        __syncthreads();
    }

#pragma unroll
    for (int ni = 0; ni < 4; ++ni) {
        const int col   = n0 + wn * 64 + ni * 16 + lane15;
        const int which = col >> 10;
        const int jj    = col & 1023;
        const float bias = (which == 0 ? bq : (which == 1 ? bk : bv))[jj];
        unsigned short* dst = (which == 0 ? qo : (which == 1 ? ko : vo));
        const int h = jj >> 6;
        const int d = jj & 63;
#pragma unroll
        for (int mi = 0; mi < 4; ++mi) {
#pragma unroll
            for (int r = 0; r < 4; ++r) {
                const int rowg = m0 + wm * 64 + mi * 16 + quad * 4 + r;
                const int bidx = rowg >> 11;
                const int t    = rowg & 2047;
                const float val = acc[mi][ni][r] + bias;
                dst[((((size_t)bidx * H_ + h) * T_ + t) << 6) + d] = f2bf(val);
            }
        }
    }
}

// ---------------------------------------------------------------------------
// Kernel 3: transpose V [B,H,T,D] -> tiled VT [bh][jt][64 d][64 keys]
// (8KB contiguous per key-tile so attn's PV loads coalesce perfectly)
// ---------------------------------------------------------------------------
__global__ __launch_bounds__(256) void transpose_v(
        const unsigned short* __restrict__ v_,
        unsigned short* __restrict__ vt)
{
    __shared__ __align__(16) unsigned short tile[64 * 80];
    const int bh = blockIdx.x >> 5;
    const int jt = blockIdx.x & 31;
    const int t0 = jt * 64;
    const unsigned short* src = v_ + (size_t)bh * T_ * D_;
    unsigned short* dst       = vt + (size_t)bh * T_ * D_ + jt * 4096;  // tile base
    const int tid = threadIdx.x;

#pragma unroll
    for (int cc = 0; cc < 2; ++cc) {
        const int c  = tid * 2 + cc;
        const int tr = c >> 3;
        const int d0 = (c & 7) * 8;
        union { short8 v; unsigned short u[8]; } val;
        val.v = *(const short8*)&src[(t0 + tr) * 64 + d0];
#pragma unroll
        for (int j = 0; j < 8; ++j)
            tile[(d0 + j) * 80 + tr] = val.u[j];
    }
    __syncthreads();
#pragma unroll
    for (int cc = 0; cc < 2; ++cc) {
        const int c  = tid * 2 + cc;
        const int dr = c >> 3;
        const int tc = (c & 7) * 8;
        *(short8*)&dst[dr * 64 + tc] = *(const short8*)&tile[dr * 80 + tc];
    }
}

// ---------------------------------------------------------------------------
// Kernel 4: flash attention, per-wave autonomous, 2-way key-sliced.
// A wave PAIR owns a 16-row q-tile: slice s takes key tiles jt = s, s+2, ...
// each slice runs its own online softmax; partials merged through LDS at end.
// 2048 blocks x 4 waves = 8192 waves (2x round 2) for latency hiding.
// ---------------------------------------------------------------------------
__global__ __launch_bounds__(256) void attn(
        const unsigned short* __restrict__ qg,   // [B,H,T,D]
        const unsigned short* __restrict__ kg,   // [B,H,T,D]
        const unsigned short* __restrict__ vtg,  // tiled [bh][jt][64][64]
        float* __restrict__ out)                 // [B,T,C] fp32
{
    __shared__ __align__(16) unsigned short Ps[4][16 * 80];  // per-wave P
    __shared__ float Ob[2][64 * 17];                         // slice-1 O^T partial
    __shared__ float Ml[2][2][16];                           // slice-1 m, l

    const int tid  = threadIdx.x;
    const int wave = tid >> 6;
    const int lane = tid & 63;
    const int lane15 = lane & 15;
    const int quad   = lane >> 4;

    const int pid = blockIdx.x * 2 + (wave >> 1);  // 0..4095 (bh, q-tile) pair id
    const int s   = wave & 1;                      // key slice
    const int p   = wave >> 1;                     // pair within block
    const int rt  = 127 - (pid & 127);             // heavy tiles first
    const int bh  = pid >> 7;
    const int b   = bh >> 4;
    const int h   = bh & 15;
    const int i0  = rt * 16;

    const unsigned short* Q  = qg  + (size_t)bh * T_ * D_;
    const unsigned short* K  = kg  + (size_t)bh * T_ * D_;
    const unsigned short* VT = vtg + (size_t)bh * T_ * D_;

    const short8 qf0 = *(const short8*)&Q[(i0 + lane15) * 64 + quad * 8];
    const short8 qf1 = *(const short8*)&Q[(i0 + lane15) * 64 + 32 + quad * 8];

    f32x4 o_acc[4];
#pragma unroll
    for (int di = 0; di < 4; ++di) o_acc[di] = (f32x4){0.f, 0.f, 0.f, 0.f};
    float m_r = -1e30f;
    float l_p = 0.f;

    unsigned short* myPs = &Ps[wave][0];

    const int jmaxE  = min(T_, i0 + 16 + SRCL_);
    const int ntiles = (jmaxE + 63) >> 6;

    for (int jt = s; jt < ntiles; jt += 2) {
        const int j0 = jt << 6;
        // ---- S^T = K Q^T
        f32x4 sv[4];
#pragma unroll
        for (int ni = 0; ni < 4; ++ni) {
            const unsigned short* Krow = &K[(j0 + ni * 16 + lane15) * 64 + quad * 8];
            short8 kf0 = *(const short8*)Krow;
            short8 kf1 = *(const short8*)(Krow + 32);
            f32x4 t = (f32x4){0.f, 0.f, 0.f, 0.f};
            t = __builtin_amdgcn_mfma_f32_16x16x32_bf16(kf0, qf0, t, 0, 0, 0);
            t = __builtin_amdgcn_mfma_f32_16x16x32_bf16(kf1, qf1, t, 0, 0, 0);
            sv[ni] = t;
        }

        const bool needMask = (j0 + 63 > i0 + SRCL_);
        float tmax = m_r;
#pragma unroll
        for (int ni = 0; ni < 4; ++ni) {
#pragma unroll
            for (int r = 0; r < 4; ++r) {
                float tv = sv[ni][r] * 0.125f;
                if (needMask) {
                    const int key = j0 + ni * 16 + quad * 4 + r;
                    if (key > i0 + lane15 + SRCL_) tv = -1e30f;
                }
                sv[ni][r] = tv;
                tmax = fmaxf(tmax, tv);
            }
        }
        tmax = fmaxf(tmax, __shfl_xor(tmax, 16));
        tmax = fmaxf(tmax, __shfl_xor(tmax, 32));
        const float alpha = __expf(m_r - tmax);
        m_r = tmax;

        float ls = 0.f;
#pragma unroll
        for (int ni = 0; ni < 4; ++ni) {
            float p0 = __expf(sv[ni][0] - tmax);
            float p1 = __expf(sv[ni][1] - tmax);
            float p2 = __expf(sv[ni][2] - tmax);
            float p3 = __expf(sv[ni][3] - tmax);
            ls += (p0 + p1) + (p2 + p3);
            uint2 w;
            w.x = (unsigned)f2bf(p0) | ((unsigned)f2bf(p1) << 16);
            w.y = (unsigned)f2bf(p2) | ((unsigned)f2bf(p3) << 16);
            *(uint2*)&myPs[lane15 * 80 + ni * 16 + quad * 4] = w;
        }
        l_p = l_p * alpha + ls;
#pragma unroll
        for (int di = 0; di < 4; ++di) o_acc[di] *= alpha;

        // same-wave DS ops are in-order; compiler inserts lgkmcnt before use.
        const short8 pf0 = *(const short8*)&myPs[lane15 * 80 + quad * 8];
        const short8 pf1 = *(const short8*)&myPs[lane15 * 80 + 32 + quad * 8];

        const unsigned short* Vt = VT + jt * 4096;   // tile-contiguous
#pragma unroll
        for (int di = 0; di < 4; ++di) {
            const unsigned short* Vrow = &Vt[(di * 16 + lane15) * 64 + quad * 8];
            short8 vf0 = *(const short8*)Vrow;
            short8 vf1 = *(const short8*)(Vrow + 32);
            o_acc[di] = __builtin_amdgcn_mfma_f32_16x16x32_bf16(vf0, pf0, o_acc[di], 0, 0, 0);
            o_acc[di] = __builtin_amdgcn_mfma_f32_16x16x32_bf16(vf1, pf1, o_acc[di], 0, 0, 0);
        }
    }

    // per-lane partial denom -> per-q total (across quads)
    float l0s = l_p + __shfl_xor(l_p, 16);
    const float l_tot = l0s + __shfl_xor(l0s, 32);

    if (s == 1) {
        // publish slice-1 partials
#pragma unroll
        for (int di = 0; di < 4; ++di)
#pragma unroll
            for (int r = 0; r < 4; ++r)
                Ob[p][(di * 16 + quad * 4 + r) * 17 + lane15] = o_acc[di][r];
        if (lane < 16) { Ml[p][0][lane] = m_r; Ml[p][1][lane] = l_tot; }
    }
    __syncthreads();
    if (s == 0) {
        const float m1 = Ml[p][0][lane15];
        const float l1 = Ml[p][1][lane15];
        const float m  = fmaxf(m_r, m1);
        const float a0 = __expf(m_r - m);
        const float a1 = __expf(m1 - m);
        const float inv = 1.0f / (l_tot * a0 + l1 * a1);
        float* orow = out + ((size_t)(b * T_ + i0 + lane15)) * C_ + h * 64 + quad * 4;
#pragma unroll
        for (int di = 0; di < 4; ++di) {
            float4 v;
            v.x = (o_acc[di][0] * a0 + Ob[p][(di * 16 + quad * 4 + 0) * 17 + lane15] * a1) * inv;
            v.y = (o_acc[di][1] * a0 + Ob[p][(di * 16 + quad * 4 + 1) * 17 + lane15] * a1) * inv;
            v.z = (o_acc[di][2] * a0 + Ob[p][(di * 16 + quad * 4 + 2) * 17 + lane15] * a1) * inv;
            v.w = (o_acc[di][3] * a0 + Ob[p][(di * 16 + quad * 4 + 3) * 17 + lane15] * a1) * inv;
            *(float4*)(orow + di * 16) = v;
        }
    }
}

// ---------------------------------------------------------------------------
// Launch
// ---------------------------------------------------------------------------
extern "C" void kernel_launch(void* const* d_in, const int* in_sizes, int n_in,
                              void* d_out, int out_size, void* d_ws, size_t ws_size,
                              hipStream_t stream) {
    const float* x  = (const float*)d_in[0];
    const float* Wq = (const float*)d_in[1];
    const float* bq = (const float*)d_in[2];
    const float* Wk = (const float*)d_in[3];
    const float* bk = (const float*)d_in[4];
    const float* Wv = (const float*)d_in[5];
    const float* bv = (const float*)d_in[6];
    float* out = (float*)d_out;

    unsigned short* xb  = (unsigned short*)d_ws;            // 4096*1024
    unsigned short* wb  = xb  + (size_t)B_ * T_ * C_;       // 3*1024*1024
    unsigned short* qb  = wb  + (size_t)3 * C_ * C_;        // B*H*T*D
    unsigned short* kb  = qb  + (size_t)B_ * H_ * T_ * D_;
    unsigned short* vb  = kb  + (size_t)B_ * H_ * T_ * D_;
    unsigned short* vtb = vb  + (size_t)B_ * H_ * T_ * D_;

    convert_all<<<7168, 256, 0, stream>>>(x, Wq, Wk, Wv, xb, wb);
    gemm_qkv<<<768, 256, 0, stream>>>(xb, wb, bq, bk, bv, qb, kb, vb);
    transpose_v<<<1024, 256, 0, stream>>>(vb, vtb);
    attn<<<2048, 256, 0, stream>>>(qb, kb, vtb, out);
}

// Round 4
// 268.936 us; speedup vs baseline: 1.6071x; 1.1885x over previous
//
#include <hip/hip_runtime.h>
#include <hip/hip_bf16.h>

// Problem constants
#define B_    2
#define T_    2048
#define C_    1024
#define H_    16
#define D_    64
#define SRCL_ 128

typedef short  short8 __attribute__((ext_vector_type(8)));   // 8 bf16 (4 VGPRs)
typedef float  f32x4  __attribute__((ext_vector_type(4)));
typedef unsigned short ushort4_t __attribute__((ext_vector_type(4)));

__device__ inline unsigned short f2bf(float f) {
    union { float f; unsigned u; } v; v.f = f;
    unsigned r = v.u + 0x7FFFu + ((v.u >> 16) & 1u);   // RNE
    return (unsigned short)(r >> 16);
}

// async global->LDS, 16B per lane; LDS dest = uniform base + lane*16
__device__ __forceinline__ void async_ld16(const void* g, void* l) {
    __builtin_amdgcn_global_load_lds(
        (const __attribute__((address_space(1))) unsigned int*)g,
        (__attribute__((address_space(3))) unsigned int*)l, 16, 0, 0);
}

// ---------------------------------------------------------------------------
// Kernel 1: fp32 -> bf16 conversion of x and the three weight matrices.
// ---------------------------------------------------------------------------
__global__ __launch_bounds__(256) void convert_all(
        const float* __restrict__ x,
        const float* __restrict__ wq,
        const float* __restrict__ wk,
        const float* __restrict__ wv,
        unsigned short* __restrict__ xb,
        unsigned short* __restrict__ wb)
{
    const int NX = (B_ * T_ * C_) / 4;
    const int NW = (C_ * C_) / 4;
    int i = blockIdx.x * 256 + threadIdx.x;
    const float4* src;
    ushort4_t* dst;
    if (i < NX)               { src = (const float4*)x;  dst = (ushort4_t*)xb;                }
    else if (i < NX + NW)     { src = (const float4*)wq; dst = (ushort4_t*)wb;                i -= NX; }
    else if (i < NX + 2*NW)   { src = (const float4*)wk; dst = (ushort4_t*)(wb + C_*C_);      i -= NX + NW; }
    else                      { src = (const float4*)wv; dst = (ushort4_t*)(wb + 2*C_*C_);    i -= NX + 2*NW; }
    float4 v = src[i];
    ushort4_t o;
    o.x = f2bf(v.x); o.y = f2bf(v.y); o.z = f2bf(v.z); o.w = f2bf(v.w);
    dst[i] = o;
}

// ---------------------------------------------------------------------------
// Kernel 2: fused QKV projection GEMM with global_load_lds width-16 staging.
// V is written directly in tiled-transposed layout [bh][jt][64 d][64 keys]
// (the separate transpose kernel is gone).
// ---------------------------------------------------------------------------
__global__ __launch_bounds__(256) void gemm_qkv(
        const unsigned short* __restrict__ xb,   // [4096,1024]
        const unsigned short* __restrict__ wb,   // [3072,1024]
        const float* __restrict__ bq,
        const float* __restrict__ bk,
        const float* __restrict__ bv,
        unsigned short* __restrict__ qo,         // [B,H,T,D]
        unsigned short* __restrict__ ko,         // [B,H,T,D]
        unsigned short* __restrict__ vto)        // tiled [bh][jt][64][64]
{
    __shared__ __align__(16) unsigned short As[128 * 32];
    __shared__ __align__(16) unsigned short Bs[128 * 32];

    const int tid  = threadIdx.x;
    const int wave = tid >> 6;
    const int lane = tid & 63;
    const int lane15 = lane & 15;
    const int quad   = lane >> 4;
    const int wm = wave >> 1;
    const int wn = wave & 1;
    const int m0 = (blockIdx.x & 31) * 128;
    const int n0 = (blockIdx.x >> 5) * 128;

    f32x4 acc[4][4];
#pragma unroll
    for (int mi = 0; mi < 4; ++mi)
#pragma unroll
        for (int ni = 0; ni < 4; ++ni)
            acc[mi][ni] = (f32x4){0.f, 0.f, 0.f, 0.f};

    const int c0   = wave * 2;
    const int rowi0 = 16 * c0 + (lane >> 2);
    const int rowi1 = 16 * (c0 + 1) + (lane >> 2);
    const int col8 = (lane & 3) * 8;

    const unsigned short* xrow0 = &xb[(m0 + rowi0) * 1024 + col8];
    const unsigned short* xrow1 = &xb[(m0 + rowi1) * 1024 + col8];
    const unsigned short* wrow0 = &wb[(n0 + rowi0) * 1024 + col8];
    const unsigned short* wrow1 = &wb[(n0 + rowi1) * 1024 + col8];

    for (int k0 = 0; k0 < 1024; k0 += 32) {
        async_ld16(xrow0 + k0, &As[c0 * 512]);
        async_ld16(xrow1 + k0, &As[(c0 + 1) * 512]);
        async_ld16(wrow0 + k0, &Bs[c0 * 512]);
        async_ld16(wrow1 + k0, &Bs[(c0 + 1) * 512]);
        __syncthreads();

        short8 a[4], bf[4];
#pragma unroll
        for (int mi = 0; mi < 4; ++mi)
            a[mi] = *(const short8*)&As[(wm * 64 + mi * 16 + lane15) * 32 + quad * 8];
#pragma unroll
        for (int ni = 0; ni < 4; ++ni)
            bf[ni] = *(const short8*)&Bs[(wn * 64 + ni * 16 + lane15) * 32 + quad * 8];
#pragma unroll
        for (int mi = 0; mi < 4; ++mi)
#pragma unroll
            for (int ni = 0; ni < 4; ++ni)
                acc[mi][ni] = __builtin_amdgcn_mfma_f32_16x16x32_bf16(a[mi], bf[ni], acc[mi][ni], 0, 0, 0);
        __syncthreads();
    }

#pragma unroll
    for (int ni = 0; ni < 4; ++ni) {
        const int col   = n0 + wn * 64 + ni * 16 + lane15;
        const int which = col >> 10;
        const int jj    = col & 1023;
        const float bias = (which == 0 ? bq : (which == 1 ? bk : bv))[jj];
        const int h = jj >> 6;
        const int d = jj & 63;
#pragma unroll
        for (int mi = 0; mi < 4; ++mi) {
#pragma unroll
            for (int r = 0; r < 4; ++r) {
                const int rowg = m0 + wm * 64 + mi * 16 + quad * 4 + r;
                const int bidx = rowg >> 11;
                const int t    = rowg & 2047;
                const unsigned short val = f2bf(acc[mi][ni][r] + bias);
                const size_t bh = (size_t)bidx * H_ + h;
                if (which == 2) {
                    // tiled-transposed V: [bh][t>>6][d][t&63]
                    vto[bh * (T_ * D_) + ((t >> 6) * 4096) + d * 64 + (t & 63)] = val;
                } else {
                    unsigned short* dst = (which == 0) ? qo : ko;
                    dst[(bh * T_ + t) * D_ + d] = val;
                }
            }
        }
    }
}

// ---------------------------------------------------------------------------
// Kernel 3: flash attention. Block = one (bh, 16-row q-tile), 4 waves =
// 4 key slices (wave s handles key tiles jt ≡ s mod 4). Per-wave online
// softmax with register prefetch of next K tile; V loads issued at
// iteration top (used after softmax). Slices merged once via LDS.
// Grid 4096 blocks >> residency (~4-6/CU) with heavy tiles first.
// ---------------------------------------------------------------------------
__global__ __launch_bounds__(256) void attn(
        const unsigned short* __restrict__ qg,   // [B,H,T,D]
        const unsigned short* __restrict__ kg,   // [B,H,T,D]
        const unsigned short* __restrict__ vtg,  // tiled [bh][jt][64][64]
        float* __restrict__ out)                 // [B,T,C] fp32
{
    __shared__ __align__(16) unsigned short Ps[4][16 * 80];  // per-wave P
    __shared__ float Ob[3][64 * 17];                         // slice 1..3 O^T partials
    __shared__ float Ml[3][2][16];                           // slice 1..3 m, l

    const int tid  = threadIdx.x;
    const int s    = tid >> 6;                   // wave = key slice 0..3
    const int lane = tid & 63;
    const int lane15 = lane & 15;
    const int quad   = lane >> 4;

    const int rt = 127 - (blockIdx.x >> 5);      // heavy q-tiles dispatched first
    const int bh = blockIdx.x & 31;
    const int b  = bh >> 4;
    const int h  = bh & 15;
    const int i0 = rt * 16;

    const unsigned short* Q  = qg  + (size_t)bh * T_ * D_;
    const unsigned short* K  = kg  + (size_t)bh * T_ * D_;
    const unsigned short* VT = vtg + (size_t)bh * T_ * D_;

    const short8 qf0 = *(const short8*)&Q[(i0 + lane15) * 64 + quad * 8];
    const short8 qf1 = *(const short8*)&Q[(i0 + lane15) * 64 + 32 + quad * 8];

    f32x4 o_acc[4];
#pragma unroll
    for (int di = 0; di < 4; ++di) o_acc[di] = (f32x4){0.f, 0.f, 0.f, 0.f};
    float m_r = -1e30f;
    float l_p = 0.f;

    unsigned short* myPs = &Ps[s][0];

    const int jmaxE  = min(T_, i0 + 16 + SRCL_);
    const int ntiles = (jmaxE + 63) >> 6;
    const int myN    = (ntiles > s) ? ((ntiles - s + 3) >> 2) : 0;

    if (myN > 0) {
        int jt = s;
        // prologue: K fragments for first tile
        short8 kc0[4], kc1[4];
#pragma unroll
        for (int ni = 0; ni < 4; ++ni) {
            const unsigned short* Krow = &K[(jt * 64 + ni * 16 + lane15) * 64 + quad * 8];
            kc0[ni] = *(const short8*)Krow;
            kc1[ni] = *(const short8*)(Krow + 32);
        }

        for (int it = 0; it < myN; ++it) {
            const int j0 = jt << 6;
            const int jn = (it + 1 < myN) ? (jt + 4) : jt;   // clamped prefetch

            // V loads for current tile (used after softmax, ~300 cyc later)
            short8 vf0[4], vf1[4];
#pragma unroll
            for (int di = 0; di < 4; ++di) {
                const unsigned short* Vrow = &VT[jt * 4096 + (di * 16 + lane15) * 64 + quad * 8];
                vf0[di] = *(const short8*)Vrow;
                vf1[di] = *(const short8*)(Vrow + 32);
            }
            // K prefetch for next tile
            short8 kn0[4], kn1[4];
#pragma unroll
            for (int ni = 0; ni < 4; ++ni) {
                const unsigned short* Krow = &K[(jn * 64 + ni * 16 + lane15) * 64 + quad * 8];
                kn0[ni] = *(const short8*)Krow;
                kn1[ni] = *(const short8*)(Krow + 32);
            }

            // ---- S^T = K Q^T (K already in regs)
            f32x4 sv[4];
#pragma unroll
            for (int ni = 0; ni < 4; ++ni) {
                f32x4 t = (f32x4){0.f, 0.f, 0.f, 0.f};
                t = __builtin_amdgcn_mfma_f32_16x16x32_bf16(kc0[ni], qf0, t, 0, 0, 0);
                t = __builtin_amdgcn_mfma_f32_16x16x32_bf16(kc1[ni], qf1, t, 0, 0, 0);
                sv[ni] = t;
            }

            const bool needMask = (j0 + 63 > i0 + SRCL_);
            float tmax = m_r;
#pragma unroll
            for (int ni = 0; ni < 4; ++ni) {
#pragma unroll
                for (int r = 0; r < 4; ++r) {
                    float tv = sv[ni][r] * 0.125f;
                    if (needMask) {
                        const int key = j0 + ni * 16 + quad * 4 + r;
                        if (key > i0 + lane15 + SRCL_) tv = -1e30f;
                    }
                    sv[ni][r] = tv;
                    tmax = fmaxf(tmax, tv);
                }
            }
            tmax = fmaxf(tmax, __shfl_xor(tmax, 16));
            tmax = fmaxf(tmax, __shfl_xor(tmax, 32));
            const float alpha = __expf(m_r - tmax);
            m_r = tmax;

            float ls = 0.f;
#pragma unroll
            for (int ni = 0; ni < 4; ++ni) {
                float p0 = __expf(sv[ni][0] - tmax);
                float p1 = __expf(sv[ni][1] - tmax);
                float p2 = __expf(sv[ni][2] - tmax);
                float p3 = __expf(sv[ni][3] - tmax);
                ls += (p0 + p1) + (p2 + p3);
                uint2 w;
                w.x = (unsigned)f2bf(p0) | ((unsigned)f2bf(p1) << 16);
                w.y = (unsigned)f2bf(p2) | ((unsigned)f2bf(p3) << 16);
                *(uint2*)&myPs[lane15 * 80 + ni * 16 + quad * 4] = w;
            }
            l_p = l_p * alpha + ls;
#pragma unroll
            for (int di = 0; di < 4; ++di) o_acc[di] *= alpha;

            // same-wave DS in-order; compiler inserts lgkmcnt before use
            const short8 pf0 = *(const short8*)&myPs[lane15 * 80 + quad * 8];
            const short8 pf1 = *(const short8*)&myPs[lane15 * 80 + 32 + quad * 8];

#pragma unroll
            for (int di = 0; di < 4; ++di) {
                o_acc[di] = __builtin_amdgcn_mfma_f32_16x16x32_bf16(vf0[di], pf0, o_acc[di], 0, 0, 0);
                o_acc[di] = __builtin_amdgcn_mfma_f32_16x16x32_bf16(vf1[di], pf1, o_acc[di], 0, 0, 0);
            }

#pragma unroll
            for (int ni = 0; ni < 4; ++ni) { kc0[ni] = kn0[ni]; kc1[ni] = kn1[ni]; }
            jt += 4;
        }
    }

    // per-lane partial denom -> per-q total (across quads)
    float l0s = l_p + __shfl_xor(l_p, 16);
    const float l_tot = l0s + __shfl_xor(l0s, 32);

    if (s > 0) {
#pragma unroll
        for (int di = 0; di < 4; ++di)
#pragma unroll
            for (int r = 0; r < 4; ++r)
                Ob[s - 1][(di * 16 + quad * 4 + r) * 17 + lane15] = o_acc[di][r];
        if (lane < 16) { Ml[s - 1][0][lane] = m_r; Ml[s - 1][1][lane] = l_tot; }
    }
    __syncthreads();
    if (s == 0) {
        float m = m_r;
#pragma unroll
        for (int k = 0; k < 3; ++k) m = fmaxf(m, Ml[k][0][lane15]);
        const float a0 = __expf(m_r - m);
        float lsum = l_tot * a0;
        float ak[3];
#pragma unroll
        for (int k = 0; k < 3; ++k) {
            ak[k] = __expf(Ml[k][0][lane15] - m);
            lsum += Ml[k][1][lane15] * ak[k];
        }
        const float inv = 1.0f / lsum;
        float* orow = out + ((size_t)(b * T_ + i0 + lane15)) * C_ + h * 64 + quad * 4;
#pragma unroll
        for (int di = 0; di < 4; ++di) {
            float4 v;
#pragma unroll
            for (int r = 0; r < 4; ++r) {
                float acc = o_acc[di][r] * a0;
#pragma unroll
                for (int k = 0; k < 3; ++k)
                    acc += Ob[k][(di * 16 + quad * 4 + r) * 17 + lane15] * ak[k];
                ((float*)&v)[r] = acc * inv;
            }
            *(float4*)(orow + di * 16) = v;
        }
    }
}

// ---------------------------------------------------------------------------
// Launch
// ---------------------------------------------------------------------------
extern "C" void kernel_launch(void* const* d_in, const int* in_sizes, int n_in,
                              void* d_out, int out_size, void* d_ws, size_t ws_size,
                              hipStream_t stream) {
    const float* x  = (const float*)d_in[0];
    const float* Wq = (const float*)d_in[1];
    const float* bq = (const float*)d_in[2];
    const float* Wk = (const float*)d_in[3];
    const float* bk = (const float*)d_in[4];
    const float* Wv = (const float*)d_in[5];
    const float* bv = (const float*)d_in[6];
    float* out = (float*)d_out;

    unsigned short* xb  = (unsigned short*)d_ws;            // 4096*1024
    unsigned short* wb  = xb  + (size_t)B_ * T_ * C_;       // 3*1024*1024
    unsigned short* qb  = wb  + (size_t)3 * C_ * C_;        // B*H*T*D
    unsigned short* kb  = qb  + (size_t)B_ * H_ * T_ * D_;
    unsigned short* vtb = kb  + (size_t)B_ * H_ * T_ * D_;  // tiled V^T

    convert_all<<<7168, 256, 0, stream>>>(x, Wq, Wk, Wv, xb, wb);
    gemm_qkv<<<768, 256, 0, stream>>>(xb, wb, bq, bk, bv, qb, kb, vtb);
    attn<<<4096, 256, 0, stream>>>(qb, kb, vtb, out);
}